// Round 1
// baseline (757.998 us; speedup 1.0000x reference)
//
#include <hip/hip_runtime.h>

// ---------------------------------------------------------------------------
// Shapes (fixed by the problem):
//   x  [2,256,64,64]   y [2,256,32,512]   z [2,128,32,512]   u [2,64,64] int
//   wq1/wk1 [128,256,3,3]  wq2/wk2 [128,128,3,3]  biases [128]
//   out a [2,4096,128] fp32
//
// Pipeline:
//   t1 = relu(conv(x, wq1))          [2,128,64,64]
//   q  = conv(t1, wq2)               [2,128,64,64]  -> qT [2,4096,128]
//   t2 = relu(conv(y, wk1))          [2,128,32,512]
//   k  = conv(t2, wk2)               [2,128,32,512] -> kT [2,512,32,128]
//   zT = transpose(z)                [2,512,32,128]
//   attn(qT,kT,zT,u) -> out
// ---------------------------------------------------------------------------

// Direct 3x3 SAME conv as implicit GEMM.
// Block tile: 128 output channels x PX pixels (one image row segment).
// 256 threads, per-thread 8 oc x (PX/16) px register tile.
// K-chunks of 8 input channels (72 k-steps) staged in LDS.
template<int IC, int IH, int IW, int PX>
__global__ __launch_bounds__(256) void conv3x3_k(
    const float* __restrict__ in,   // [B, IC, IH, IW]
    const float* __restrict__ wgt,  // [128, IC, 3, 3]
    const float* __restrict__ bias, // [128]
    float* __restrict__ out,        // [B, 128, IH, IW]
    int relu)
{
  constexpr int OC  = 128;
  constexpr int ICC = 8;
  constexpr int KK  = ICC * 9;          // 72
  constexpr int PPX = PX / 16;          // pixels per thread (2 or 4)
  constexpr int WROW = OC + 4;          // pad 4 floats: rows stay 16B aligned
  __shared__ float Wl[KK][WROW];
  __shared__ float Il[ICC][3][PX + 4];

  const int tid = threadIdx.x;
  const int tc  = tid & 15;             // pixel group
  const int tr  = tid >> 4;             // oc group: oc = tr*8
  constexpr int TPR = IW / PX;          // tiles per image row
  const int tile = blockIdx.x;
  const int b    = blockIdx.y;
  const int h0   = tile / TPR;
  const int w0   = (tile % TPR) * PX;

  float acc[8][PPX];
  #pragma unroll
  for (int i = 0; i < 8; ++i)
    #pragma unroll
    for (int p = 0; p < PPX; ++p) acc[i][p] = 0.f;

  for (int ic0 = 0; ic0 < IC; ic0 += ICC) {
    // ---- stage weights: Wl[kk][oc] = wgt[oc][ic0*9 + kk], kk in [0,72)
    #pragma unroll
    for (int i = 0; i < (KK * OC) / 256; ++i) {
      int flat = tid + i * 256;
      int oc = flat / KK, kk = flat - oc * KK;
      Wl[kk][oc] = wgt[oc * (IC * 9) + ic0 * 9 + kk];
    }
    // ---- stage input rows with halo (zero padded)
    constexpr int ILN = ICC * 3 * (PX + 2);
    for (int flat = tid; flat < ILN; flat += 256) {
      int j   = flat % (PX + 2);
      int t2  = flat / (PX + 2);
      int rr  = t2 % 3;
      int icc = t2 / 3;
      int hh = h0 + rr - 1;
      int ww = w0 + j - 1;
      float v = 0.f;
      if ((unsigned)hh < (unsigned)IH && (unsigned)ww < (unsigned)IW)
        v = in[((b * IC + ic0 + icc) * IH + hh) * IW + ww];
      Il[icc][rr][j] = v;
    }
    __syncthreads();

    for (int icc = 0; icc < ICC; ++icc) {
      #pragma unroll
      for (int r = 0; r < 3; ++r) {
        float row[PPX + 2];
        #pragma unroll
        for (int j = 0; j < PPX + 2; ++j) row[j] = Il[icc][r][tc * PPX + j];
        #pragma unroll
        for (int s = 0; s < 3; ++s) {
          const int kk = icc * 9 + r * 3 + s;
          const float4 a0 = *reinterpret_cast<const float4*>(&Wl[kk][tr * 8]);
          const float4 a1 = *reinterpret_cast<const float4*>(&Wl[kk][tr * 8 + 4]);
          #pragma unroll
          for (int p = 0; p < PPX; ++p) {
            const float bv = row[p + s];
            acc[0][p] = fmaf(a0.x, bv, acc[0][p]);
            acc[1][p] = fmaf(a0.y, bv, acc[1][p]);
            acc[2][p] = fmaf(a0.z, bv, acc[2][p]);
            acc[3][p] = fmaf(a0.w, bv, acc[3][p]);
            acc[4][p] = fmaf(a1.x, bv, acc[4][p]);
            acc[5][p] = fmaf(a1.y, bv, acc[5][p]);
            acc[6][p] = fmaf(a1.z, bv, acc[6][p]);
            acc[7][p] = fmaf(a1.w, bv, acc[7][p]);
          }
        }
      }
    }
    __syncthreads();
  }

  // ---- epilogue: bias (+ optional relu), write [B,128,IH,IW]
  #pragma unroll
  for (int i = 0; i < 8; ++i) {
    const int oc = tr * 8 + i;
    const float bb = bias[oc];
    #pragma unroll
    for (int p = 0; p < PPX; ++p) {
      float v = acc[i][p] + bb;
      if (relu) v = fmaxf(v, 0.f);
      out[((b * OC + oc) * IH + h0) * IW + w0 + tc * PPX + p] = v;
    }
  }
}

// Transpose [B][C][H][W] -> [B][W][H][C]. C, W multiples of 32.
// grid (W/32, C/32, B*H), block (32,8)
__global__ void transpose_cw_k(const float* __restrict__ in,
                               float* __restrict__ out,
                               int C, int H, int W)
{
  __shared__ float tile[32][33];
  const int bh = blockIdx.z;
  const int b = bh / H, h = bh % H;
  const int w0 = blockIdx.x * 32, c0 = blockIdx.y * 32;
  const int tx = threadIdx.x, ty = threadIdx.y;
  #pragma unroll
  for (int k2 = 0; k2 < 4; ++k2) {
    int c = c0 + ty + k2 * 8;
    tile[ty + k2 * 8][tx] = in[((b * C + c) * H + h) * W + w0 + tx];
  }
  __syncthreads();
  #pragma unroll
  for (int k2 = 0; k2 < 4; ++k2) {
    int w = w0 + ty + k2 * 8;
    out[((b * (long)W + w) * H + h) * C + c0 + tx] = tile[tx][ty + k2 * 8];
  }
}

// Attention: one block per (b, n). 128 threads (2 waves).
//   qT [B,4096,128], kT/zT [B,512,32,128], u [B,4096] -> out [B,4096,128]
__global__ __launch_bounds__(128) void attn_k(
    const float* __restrict__ qT, const float* __restrict__ kT,
    const float* __restrict__ zT, const int* __restrict__ u,
    float* __restrict__ out)
{
  constexpr float SCALE = 0.08838834764831845f;  // 128^-0.5
  const int n = blockIdx.x, b = blockIdx.y;
  const int t = threadIdx.x;

  __shared__ float qs[128];
  __shared__ float logit[32];
  __shared__ float el[32];

  int widx = u[b * 4096 + n];
  widx = widx < 0 ? 0 : (widx > 511 ? 511 : widx);

  qs[t] = qT[(b * 4096 + n) * 128 + t];
  __syncthreads();

  // logits: thread t handles (h = t/4, quad = t%4) over 32 channels each
  const int h = t >> 2, quad = t & 3;
  const float* kcol = kT + (((long)b * 512 + widx) * 32 + h) * 128 + quad * 32;
  float p = 0.f;
  #pragma unroll
  for (int j = 0; j < 32; j += 4) {
    const float4 kv = *reinterpret_cast<const float4*>(kcol + j);
    p = fmaf(qs[quad * 32 + j + 0], kv.x, p);
    p = fmaf(qs[quad * 32 + j + 1], kv.y, p);
    p = fmaf(qs[quad * 32 + j + 2], kv.z, p);
    p = fmaf(qs[quad * 32 + j + 3], kv.w, p);
  }
  p += __shfl_xor(p, 1);
  p += __shfl_xor(p, 2);
  if (quad == 0) logit[h] = p * SCALE;
  __syncthreads();

  // softmax over 32 (redundant per-thread max; exp staged once in LDS)
  float m = -3.4e38f;
  #pragma unroll
  for (int h2 = 0; h2 < 32; ++h2) m = fmaxf(m, logit[h2]);
  if (t < 32) el[t] = __expf(logit[t] - m);
  __syncthreads();
  float den = 0.f;
  #pragma unroll
  for (int h2 = 0; h2 < 32; ++h2) den += el[h2];

  // weighted sum of V: thread t owns channel c = t
  const float* zcol = zT + (((long)b * 512 + widx) * 32) * 128 + t;
  float o = 0.f;
  #pragma unroll
  for (int h2 = 0; h2 < 32; ++h2) o = fmaf(el[h2], zcol[h2 * 128], o);
  out[((long)(b * 4096 + n)) * 128 + t] = o / den;
}

extern "C" void kernel_launch(void* const* d_in, const int* in_sizes, int n_in,
                              void* d_out, int out_size, void* d_ws, size_t ws_size,
                              hipStream_t stream) {
  const float* x   = (const float*)d_in[0];
  const float* y   = (const float*)d_in[1];
  const float* z   = (const float*)d_in[2];
  const int*   u   = (const int*)  d_in[3];
  const float* wq1 = (const float*)d_in[4];
  const float* bq1 = (const float*)d_in[5];
  const float* wq2 = (const float*)d_in[6];
  const float* bq2 = (const float*)d_in[7];
  const float* wk1 = (const float*)d_in[8];
  const float* bk1 = (const float*)d_in[9];
  const float* wk2 = (const float*)d_in[10];
  const float* bk2 = (const float*)d_in[11];
  float* out = (float*)d_out;
  float* ws  = (float*)d_ws;

  // workspace regions (floats), with lifetime-based reuse; peak 40 MB
  float* t1 = ws + 0;        // [2,128,64,64]   1,048,576
  float* q  = ws + 1048576;  // [2,128,64,64]   1,048,576
  float* qT = ws + 0;        // reuse t1 (dead after conv B)
  float* t2 = ws + 2097152;  // [2,128,32,512]  4,194,304
  float* k  = ws + 6291456;  // [2,128,32,512]  4,194,304
  float* kT = ws + 2097152;  // reuse t2 (dead after conv D)
  float* zT = ws + 6291456;  // reuse k (dead after kT transpose)

  // q path
  conv3x3_k<256, 64, 64, 32><<<dim3(128, 2), 256, 0, stream>>>(x,  wq1, bq1, t1, 1);
  conv3x3_k<128, 64, 64, 32><<<dim3(128, 2), 256, 0, stream>>>(t1, wq2, bq2, q,  0);
  transpose_cw_k<<<dim3(128, 4, 2), dim3(32, 8), 0, stream>>>(q, qT, 128, 1, 4096);

  // k path
  conv3x3_k<256, 32, 512, 64><<<dim3(256, 2), 256, 0, stream>>>(y,  wk1, bk1, t2, 1);
  conv3x3_k<128, 32, 512, 64><<<dim3(256, 2), 256, 0, stream>>>(t2, wk2, bk2, k,  0);
  transpose_cw_k<<<dim3(16, 4, 64), dim3(32, 8), 0, stream>>>(k, kT, 128, 32, 512);

  // v path (no conv, just gatherable layout)
  transpose_cw_k<<<dim3(16, 4, 64), dim3(32, 8), 0, stream>>>(z, zT, 128, 32, 512);

  // fused gather + attention
  attn_k<<<dim3(4096, 2), 128, 0, stream>>>(qT, kT, zT, u, out);
}

// Round 2
// 301.137 us; speedup vs baseline: 2.5171x; 2.5171x over previous
//
#include <hip/hip_runtime.h>
#include <hip/hip_bf16.h>

// ---------------------------------------------------------------------------
// x [2,256,64,64]  y [2,256,32,512]  z [2,128,32,512]  u [2,64,64] int
// wq1/wk1 [128,256,3,3]  wq2/wk2 [128,128,3,3]  biases [128]
// out [2,4096,128] fp32
//
// All convs via split-bf16 MFMA (hi/lo decomposition, 3 MFMAs per product).
// Everything channels-last:
//   xT [2,64,64,256] -> conv -> t1q [2,64,64,128] -> conv -> q_cl [2,4096,128]
//   yT [2,32,512,256] -> conv -> t2k -> conv -> k_cl [2,32,512,128]
//   z  -> z_cl [2,32,512,128]
//   attn(q_cl, k_cl, z_cl, u) -> out
// ---------------------------------------------------------------------------

typedef __attribute__((ext_vector_type(8))) __bf16 bf16x8;
typedef __attribute__((ext_vector_type(4))) float f32x4;
typedef unsigned short u16;

#define MFMA16(A, B, C) __builtin_amdgcn_mfma_f32_16x16x32_bf16((A), (B), (C), 0, 0, 0)

__device__ __forceinline__ void cvt_hilo(float v, u16& h, u16& l) {
  __hip_bfloat16 hb = __float2bfloat16(v);
  float hf = __bfloat162float(hb);
  __hip_bfloat16 lb = __float2bfloat16(v - hf);
  h = __builtin_bit_cast(u16, hb);
  l = __builtin_bit_cast(u16, lb);
}

// Pack conv weights [128][IC][3][3] fp32 -> wpk hi plane [9][IC/32][128][32]
// bf16-bits, then lo plane at offset 9*(IC/32)*128*32.
__global__ __launch_bounds__(256) void pack_w_k(
    const float* __restrict__ w, u16* __restrict__ wpk, int IC)
{
  const int t = blockIdx.x * 256 + threadIdx.x;
  if (t >= 128 * IC) return;
  const int oc = t / IC, ic = t % IC;
  const int icb = ic >> 5, icl = ic & 31;
  const int ICB = IC >> 5;
  const int WTOT = 9 * ICB * 128 * 32;
  #pragma unroll
  for (int rs = 0; rs < 9; ++rs) {
    float v = w[(oc * IC + ic) * 9 + rs];
    u16 h, l;
    cvt_hilo(v, h, l);
    int idx = ((rs * ICB + icb) * 128 + oc) * 32 + icl;
    wpk[idx] = h;
    wpk[WTOT + idx] = l;
  }
}

// [B][C][H][W] -> [B][H][W][C]  (channels-last). grid (W/32, C/32, B*H), block (32,8)
__global__ void transpose_cl_k(const float* __restrict__ in,
                               float* __restrict__ out,
                               int C, int H, int W)
{
  __shared__ float tile[32][33];
  const int bh = blockIdx.z;
  const int b = bh / H, h = bh % H;
  const int w0 = blockIdx.x * 32, c0 = blockIdx.y * 32;
  const int tx = threadIdx.x, ty = threadIdx.y;
  #pragma unroll
  for (int k2 = 0; k2 < 4; ++k2) {
    int c = c0 + ty + k2 * 8;
    tile[ty + k2 * 8][tx] = in[(((long)b * C + c) * H + h) * W + w0 + tx];
  }
  __syncthreads();
  #pragma unroll
  for (int k2 = 0; k2 < 4; ++k2) {
    int w = w0 + ty + k2 * 8;
    out[(((long)b * H + h) * W + w) * C + c0 + tx] = tile[tx][ty + k2 * 8];
  }
}

// 3x3 SAME conv, channels-last in/out, split-bf16 MFMA implicit GEMM.
// Block tile: 64 oc (M half, from blockIdx.z&1) x PXB pixels of one row.
// 256 threads = 4 waves; wave covers PXB/4 pixels (NF = PXB/64 n-frags).
// grid (IW/PXB, IH, B*2).
template<int IC, int IH, int IW, int PXB>
__global__ __launch_bounds__(256) void conv3x3_mfma_k(
    const float* __restrict__ in_cl,   // [B][IH][IW][IC]
    const u16*   __restrict__ wpk,     // packed weights (hi plane + lo plane)
    const float* __restrict__ bias,    // [128]
    float* __restrict__ out_cl,        // [B][IH][IW][128]
    int relu)
{
  constexpr int ICB  = IC / 32;
  constexpr int PP   = PXB + 2;        // staged pixels incl. halo
  constexpr int PPp  = PP + 2;         // padded stride
  constexpr int NF   = PXB / 64;       // n-frags per wave (1 or 2)
  constexpr int WTOT = 9 * ICB * 128 * 32;
  constexpr int PLANE = 3 * PPp * 32;  // ushorts per hi/lo input plane

  __shared__ __align__(16) unsigned char smem[(PLANE * 2 + 4096) * 2];
  u16* lds_hi = (u16*)smem;
  u16* lds_lo = lds_hi + PLANE;
  u16* lds_w  = lds_lo + PLANE;        // [hi 2048][lo 2048] = 64 oc x 32 ic
  float* lds_out = (float*)smem;       // epilogue overlay [PXB][64]

  const int tid  = threadIdx.x;
  const int wv   = tid >> 6;
  const int lane = tid & 63;
  const int lm   = lane & 15;          // pixel / oc-row selector
  const int lq   = lane >> 4;          // k-group
  const int bz   = blockIdx.z;
  const int b    = bz >> 1;
  const int oc0  = (bz & 1) * 64;
  const int h0   = blockIdx.y;
  const int w0   = blockIdx.x * PXB;
  const int wbase = wv * (PXB / 4);    // wave's pixel base

  f32x4 acc[4][NF];
  #pragma unroll
  for (int mf = 0; mf < 4; ++mf)
    #pragma unroll
    for (int nf = 0; nf < NF; ++nf) acc[mf][nf] = (f32x4)0.f;

  for (int icb = 0; icb < ICB; ++icb) {
    __syncthreads();  // prior iter done reading lds_in / lds_w
    // ---- stage input rows h0-1..h0+1, pixels w0-1..w0+PXB, 32 ic, as hi/lo bf16
    constexpr int TOT4 = 3 * PP * 8;   // float4 groups
    for (int i4 = tid; i4 < TOT4; i4 += 256) {
      const int icg = i4 & 7;
      const int rest = i4 >> 3;
      const int px = rest % PP;
      const int r  = rest / PP;
      const int h = h0 + r - 1, w = w0 + px - 1;
      float4 v = make_float4(0.f, 0.f, 0.f, 0.f);
      if ((unsigned)h < (unsigned)IH && (unsigned)w < (unsigned)IW)
        v = *reinterpret_cast<const float4*>(
              &in_cl[(((long)b * IH + h) * IW + w) * IC + icb * 32 + icg * 4]);
      u16 h4[4], l4[4];
      cvt_hilo(v.x, h4[0], l4[0]);
      cvt_hilo(v.y, h4[1], l4[1]);
      cvt_hilo(v.z, h4[2], l4[2]);
      cvt_hilo(v.w, h4[3], l4[3]);
      const int idx = (r * PPp + px) * 32 + icg * 4;
      *reinterpret_cast<ushort4*>(&lds_hi[idx]) = make_ushort4(h4[0], h4[1], h4[2], h4[3]);
      *reinterpret_cast<ushort4*>(&lds_lo[idx]) = make_ushort4(l4[0], l4[1], l4[2], l4[3]);
    }

    for (int rs = 0; rs < 9; ++rs) {
      if (rs > 0) __syncthreads();     // prev mfma done reading lds_w
      // ---- stage this shift's 64x32 weight tile (hi + lo), 4 KB each
      {
        const u16* wsrc_hi = wpk + ((rs * ICB + icb) * 128 + oc0) * 32;
        const u16* wsrc_lo = wsrc_hi + WTOT;
        reinterpret_cast<uint4*>(lds_w)[tid] =
            reinterpret_cast<const uint4*>(wsrc_hi)[tid];
        reinterpret_cast<uint4*>(lds_w + 2048)[tid] =
            reinterpret_cast<const uint4*>(wsrc_lo)[tid];
      }
      __syncthreads();                 // weights (and input on rs==0) visible

      const int r = rs / 3, s = rs % 3;
      // ---- B fragments (pixels), hi and lo
      bf16x8 bhi[NF], blo[NF];
      #pragma unroll
      for (int nf = 0; nf < NF; ++nf) {
        const int px = wbase + nf * 16 + lm + s;   // staged slot (w0-1 origin)
        const int idx = (r * PPp + px) * 32 + lq * 8;
        bhi[nf] = *reinterpret_cast<const bf16x8*>(&lds_hi[idx]);
        blo[nf] = *reinterpret_cast<const bf16x8*>(&lds_lo[idx]);
      }
      // ---- A fragments (weights) + 3-term split MFMA
      #pragma unroll
      for (int mf = 0; mf < 4; ++mf) {
        const int aidx = (mf * 16 + lm) * 32 + lq * 8;
        bf16x8 ahi = *reinterpret_cast<const bf16x8*>(&lds_w[aidx]);
        bf16x8 alo = *reinterpret_cast<const bf16x8*>(&lds_w[2048 + aidx]);
        #pragma unroll
        for (int nf = 0; nf < NF; ++nf) {
          acc[mf][nf] = MFMA16(ahi, bhi[nf], acc[mf][nf]);
          acc[mf][nf] = MFMA16(ahi, blo[nf], acc[mf][nf]);
          acc[mf][nf] = MFMA16(alo, bhi[nf], acc[mf][nf]);
        }
      }
    }
  }

  // ---- epilogue: bias/relu, stage [px][oc] in LDS, coalesced global write
  __syncthreads();
  #pragma unroll
  for (int mf = 0; mf < 4; ++mf)
    #pragma unroll
    for (int nf = 0; nf < NF; ++nf)
      #pragma unroll
      for (int reg = 0; reg < 4; ++reg) {
        const int px = wbase + nf * 16 + lm;
        const int oc = mf * 16 + lq * 4 + reg;
        float v = acc[mf][nf][reg] + bias[oc0 + oc];
        if (relu) v = fmaxf(v, 0.f);
        lds_out[px * 64 + oc] = v;
      }
  __syncthreads();
  constexpr int TOTW4 = PXB * 16;      // float4 groups of [PXB][64]
  for (int i = tid; i < TOTW4; i += 256) {
    const int px = i >> 4;
    const int og = (i & 15) * 4;
    *reinterpret_cast<float4*>(
        &out_cl[(((long)b * IH + h0) * IW + w0 + px) * 128 + oc0 + og]) =
        *reinterpret_cast<const float4*>(&lds_out[px * 64 + og]);
  }
}

// Attention: one block per (b, n). 128 threads.
// q_cl [B,4096,128], k_cl/z_cl [B,32,512,128], u [B,4096] -> out [B,4096,128]
__global__ __launch_bounds__(128) void attn_k(
    const float* __restrict__ q_cl, const float* __restrict__ k_cl,
    const float* __restrict__ z_cl, const int* __restrict__ u,
    float* __restrict__ out)
{
  constexpr float SCALE = 0.08838834764831845f;  // 128^-0.5
  const int n = blockIdx.x, b = blockIdx.y;
  const int t = threadIdx.x;

  __shared__ float qs[128];
  __shared__ float logit[32];
  __shared__ float el[32];

  int widx = u[b * 4096 + n];
  widx = widx < 0 ? 0 : (widx > 511 ? 511 : widx);

  qs[t] = q_cl[((long)b * 4096 + n) * 128 + t];
  __syncthreads();

  const int h = t >> 2, quad = t & 3;
  const float* kcol = k_cl + (((long)b * 32 + h) * 512 + widx) * 128 + quad * 32;
  float p = 0.f;
  #pragma unroll
  for (int j = 0; j < 32; j += 4) {
    const float4 kv = *reinterpret_cast<const float4*>(kcol + j);
    p = fmaf(qs[quad * 32 + j + 0], kv.x, p);
    p = fmaf(qs[quad * 32 + j + 1], kv.y, p);
    p = fmaf(qs[quad * 32 + j + 2], kv.z, p);
    p = fmaf(qs[quad * 32 + j + 3], kv.w, p);
  }
  p += __shfl_xor(p, 1);
  p += __shfl_xor(p, 2);
  if (quad == 0) logit[h] = p * SCALE;
  __syncthreads();

  float m = -3.4e38f;
  #pragma unroll
  for (int h2 = 0; h2 < 32; ++h2) m = fmaxf(m, logit[h2]);
  if (t < 32) el[t] = __expf(logit[t] - m);
  __syncthreads();
  float den = 0.f;
  #pragma unroll
  for (int h2 = 0; h2 < 32; ++h2) den += el[h2];

  const float* zcol = z_cl + ((long)b * 32 * 512 + widx) * 128 + t;
  float o = 0.f;
  #pragma unroll
  for (int h2 = 0; h2 < 32; ++h2) o = fmaf(el[h2], zcol[(long)h2 * 512 * 128], o);
  out[((long)b * 4096 + n) * 128 + t] = o / den;
}

extern "C" void kernel_launch(void* const* d_in, const int* in_sizes, int n_in,
                              void* d_out, int out_size, void* d_ws, size_t ws_size,
                              hipStream_t stream) {
  const float* x   = (const float*)d_in[0];
  const float* y   = (const float*)d_in[1];
  const float* z   = (const float*)d_in[2];
  const int*   u   = (const int*)  d_in[3];
  const float* wq1 = (const float*)d_in[4];
  const float* bq1 = (const float*)d_in[5];
  const float* wq2 = (const float*)d_in[6];
  const float* bq2 = (const float*)d_in[7];
  const float* wk1 = (const float*)d_in[8];
  const float* bk1 = (const float*)d_in[9];
  const float* wk2 = (const float*)d_in[10];
  const float* bk2 = (const float*)d_in[11];
  float* out  = (float*)d_out;
  float* ws_f = (float*)d_ws;

  // workspace arena (float offsets); total 18,710,528 floats = 74.9 MB
  float* yT   = ws_f + 0;          // 8,388,608  [2,32,512,256]
  float* k_cl = ws_f + 0;          // 4,194,304  (over dead yT)
  float* xT   = ws_f + 8388608;    // 2,097,152  [2,64,64,256]
  float* t2k  = ws_f + 8388608;    // 4,194,304  (over dead xT)
  float* t1q  = ws_f + 12582912;   // 1,048,576  [2,64,64,128]
  float* z_cl = ws_f + 12582912;   // 4,194,304  (over dead t1q)
  float* q_cl = ws_f + 16777216;   // 1,048,576  [2,4096,128]
  u16* wpk_q1 = (u16*)(ws_f + 17825792);   // 589,824 u16 (hi+lo)
  u16* wpk_q2 = wpk_q1 + 589824;           // 294,912
  u16* wpk_k1 = wpk_q2 + 294912;           // 589,824
  u16* wpk_k2 = wpk_k1 + 589824;           // 294,912

  // ---- weight packing (hi/lo bf16, fragment-friendly layout)
  pack_w_k<<<dim3(128), 256, 0, stream>>>(wq1, wpk_q1, 256);
  pack_w_k<<<dim3(64),  256, 0, stream>>>(wq2, wpk_q2, 128);
  pack_w_k<<<dim3(128), 256, 0, stream>>>(wk1, wpk_k1, 256);
  pack_w_k<<<dim3(64),  256, 0, stream>>>(wk2, wpk_k2, 128);

  // ---- q path
  transpose_cl_k<<<dim3(2, 8, 128), dim3(32, 8), 0, stream>>>(x, xT, 256, 64, 64);
  conv3x3_mfma_k<256, 64, 64, 64><<<dim3(1, 64, 4), 256, 0, stream>>>(xT, wpk_q1, bq1, t1q, 1);
  conv3x3_mfma_k<128, 64, 64, 64><<<dim3(1, 64, 4), 256, 0, stream>>>(t1q, wpk_q2, bq2, q_cl, 0);

  // ---- k path
  transpose_cl_k<<<dim3(16, 8, 64), dim3(32, 8), 0, stream>>>(y, yT, 256, 32, 512);
  conv3x3_mfma_k<256, 32, 512, 128><<<dim3(4, 32, 4), 256, 0, stream>>>(yT, wpk_k1, bk1, t2k, 1);
  transpose_cl_k<<<dim3(16, 4, 64), dim3(32, 8), 0, stream>>>(z, z_cl, 128, 32, 512);
  conv3x3_mfma_k<128, 32, 512, 128><<<dim3(4, 32, 4), 256, 0, stream>>>(t2k, wpk_k2, bk2, k_cl, 0);

  // ---- fused gather + attention
  attn_k<<<dim3(4096, 2), 128, 0, stream>>>(q_cl, k_cl, z_cl, u, out);
}

// Round 3
// 224.242 us; speedup vs baseline: 3.3803x; 1.3429x over previous
//
#include <hip/hip_runtime.h>
#include <hip/hip_bf16.h>

// ---------------------------------------------------------------------------
// x [2,256,64,64]  y [2,256,32,512]  z [2,128,32,512]  u [2,64,64] int
// wq1/wk1 [128,256,3,3]  wq2/wk2 [128,128,3,3]  biases [128]
// out [2,4096,128] fp32
//
// Split-bf16 MFMA convs (hi/lo, 3 MFMAs/product).
// Inputs pre-converted once to halo-padded hi/lo bf16 planes
//   [B][H+2][IC/32][W+2][32]  (zero halos -> no bounds checks).
// Conv main loop: B-fragments direct from global (L1/L2), weights staged in
// LDS once per 32-ic chunk (XOR-swizzled), 2 barriers per chunk.
// ---------------------------------------------------------------------------

typedef __attribute__((ext_vector_type(8))) __bf16 bf16x8;
typedef __attribute__((ext_vector_type(4))) float f32x4;
typedef unsigned short u16;

#define MFMA16(A, B, C) __builtin_amdgcn_mfma_f32_16x16x32_bf16((A), (B), (C), 0, 0, 0)

__device__ __forceinline__ void cvt_hilo(float v, u16& h, u16& l) {
  __hip_bfloat16 hb = __float2bfloat16(v);
  float hf = __bfloat162float(hb);
  __hip_bfloat16 lb = __float2bfloat16(v - hf);
  h = __builtin_bit_cast(u16, hb);
  l = __builtin_bit_cast(u16, lb);
}

// Pack conv weights [128][IC][3][3] fp32 -> hi plane [9][IC/32][128][32],
// lo plane at +9*(IC/32)*128*32. (A-fragment-major.)
__global__ __launch_bounds__(256) void pack_w_k(
    const float* __restrict__ w, u16* __restrict__ wpk, int IC)
{
  const int t = blockIdx.x * 256 + threadIdx.x;
  if (t >= 128 * IC) return;
  const int oc = t / IC, ic = t % IC;
  const int icb = ic >> 5, icl = ic & 31;
  const int ICB = IC >> 5;
  const int WTOT = 9 * ICB * 128 * 32;
  #pragma unroll
  for (int rs = 0; rs < 9; ++rs) {
    float v = w[(oc * IC + ic) * 9 + rs];
    u16 h, l;
    cvt_hilo(v, h, l);
    int idx = ((rs * ICB + icb) * 128 + oc) * 32 + icl;
    wpk[idx] = h;
    wpk[WTOT + idx] = l;
  }
}

// Zero the halo of one plane [B=2][H2][ICB][W2][32].
__global__ void zero_halo_k(u16* __restrict__ p, int H2, int ICB, int W2)
{
  const int B_ = 2;
  const long rows_total = (long)B_ * ICB * 2 * W2 * 32;
  const long cols_total = (long)B_ * ICB * (H2 - 2) * 2 * 32;
  long t = (long)blockIdx.x * 256 + threadIdx.x;
  if (t < rows_total) {
    int slab = (int)(t / (W2 * 32));
    int rem  = (int)(t % (W2 * 32));
    int b = slab / (ICB * 2), r2 = slab % (ICB * 2);
    int icb = r2 >> 1;
    int h = (r2 & 1) ? H2 - 1 : 0;
    p[(((long)b * H2 + h) * ICB + icb) * (long)W2 * 32 + rem] = 0;
  } else {
    long t2 = t - rows_total;
    if (t2 < cols_total) {
      int stripe = (int)(t2 / 32), icl = (int)(t2 % 32);
      int per_b = ICB * (H2 - 2) * 2;
      int b = stripe / per_b, r3 = stripe % per_b;
      int icb = r3 / ((H2 - 2) * 2), r4 = r3 % ((H2 - 2) * 2);
      int h = 1 + (r4 >> 1);
      int w = (r4 & 1) ? W2 - 1 : 0;
      p[((((long)b * H2 + h) * ICB + icb) * W2 + w) * 32 + icl] = 0;
    }
  }
}

// [B,C,H,W] fp32 -> hi/lo planes [B][H+2][C/32][W+2][32] (interior only).
// grid (W/32, C/32, B*H), block (32,8)
__global__ void cvt_pad_k(const float* __restrict__ in,
                          u16* __restrict__ oh, u16* __restrict__ ol,
                          int C, int H, int W)
{
  __shared__ float tile[32][33];
  const int bh = blockIdx.z;
  const int b = bh / H, h = bh % H;
  const int w0 = blockIdx.x * 32, icb = blockIdx.y;
  const int tx = threadIdx.x, ty = threadIdx.y;
  #pragma unroll
  for (int k2 = 0; k2 < 4; ++k2) {
    int c = icb * 32 + ty + k2 * 8;
    tile[ty + k2 * 8][tx] = in[(((long)b * C + c) * H + h) * W + w0 + tx];
  }
  __syncthreads();
  const int H2 = H + 2, W2 = W + 2, ICB = C >> 5;
  #pragma unroll
  for (int k2 = 0; k2 < 4; ++k2) {
    int w = w0 + ty + k2 * 8;
    float v = tile[tx][ty + k2 * 8];
    u16 hh, ll;
    cvt_hilo(v, hh, ll);
    long o = ((((long)b * H2 + h + 1) * ICB + icb) * W2 + (w + 1)) * 32 + tx;
    oh[o] = hh;
    ol[o] = ll;
  }
}

// [B][C][H][W] -> [B][H][W][C] fp32 (for z). grid (W/32, C/32, B*H), block (32,8)
__global__ void transpose_cl_k(const float* __restrict__ in,
                               float* __restrict__ out,
                               int C, int H, int W)
{
  __shared__ float tile[32][33];
  const int bh = blockIdx.z;
  const int b = bh / H, h = bh % H;
  const int w0 = blockIdx.x * 32, c0 = blockIdx.y * 32;
  const int tx = threadIdx.x, ty = threadIdx.y;
  #pragma unroll
  for (int k2 = 0; k2 < 4; ++k2) {
    int c = c0 + ty + k2 * 8;
    tile[ty + k2 * 8][tx] = in[(((long)b * C + c) * H + h) * W + w0 + tx];
  }
  __syncthreads();
  #pragma unroll
  for (int k2 = 0; k2 < 4; ++k2) {
    int w = w0 + ty + k2 * 8;
    out[(((long)b * H + h) * W + w) * C + c0 + tx] = tile[tx][ty + k2 * 8];
  }
}

// 3x3 SAME conv on padded hi/lo bf16 planes. 256 threads = 4 waves.
// Block: 64 oc (blockIdx.z&1) x PXB pixels of row blockIdx.y.
// OUTPAD=0: write fp32 [B][IH][IW][128]. OUTPAD=1: write padded hi/lo planes
// [B][IH+2][4][IW+2][32] (input layout of the next conv).
template<int IC, int IH, int IW, int PXB, int OUTPAD>
__global__ __launch_bounds__(256) void conv3x3_mfma_k(
    const u16* __restrict__ in_hi, const u16* __restrict__ in_lo,
    const u16* __restrict__ wpk, const float* __restrict__ bias,
    float* __restrict__ outf, u16* __restrict__ out_hi, u16* __restrict__ out_lo,
    int relu)
{
  constexpr int ICB = IC / 32;
  constexpr int H2 = IH + 2, W2 = IW + 2;
  constexpr int NF = PXB / 64;
  constexpr int WTOT = 9 * ICB * 128 * 32;

  // weights: [rs][plane][64 oc][32 ic] u16, XOR-swizzled; epilogue overlays.
  __shared__ __align__(16) u16 smem[9 * 2 * 64 * 32];   // 73728 B

  const int tid = threadIdx.x;
  const int lane = tid & 63, wv = tid >> 6;
  const int lm = lane & 15, lq = lane >> 4;
  const int b = blockIdx.z >> 1;
  const int oc0 = (blockIdx.z & 1) * 64;
  const int h0 = blockIdx.y;
  const int w0 = blockIdx.x * PXB;
  const int wbase = wv * (PXB / 4);
  const int lane_b_off = (wbase + lm) * 32 + lq * 8;

  f32x4 acc[4][NF];
  #pragma unroll
  for (int mf = 0; mf < 4; ++mf)
    #pragma unroll
    for (int nf = 0; nf < NF; ++nf) acc[mf][nf] = (f32x4)0.f;

  for (int icb = 0; icb < ICB; ++icb) {
    __syncthreads();
    // ---- stage all 9 shifts' 64x32 hi+lo weight tiles (XOR-swizzled)
    #pragma unroll
    for (int j0 = 0; j0 < 18; ++j0) {       // 4608 16B-chunks / 256 threads
      const int j = j0 * 256 + tid;
      const int i8 = j & 3;
      const int oc = (j >> 2) & 63;
      const int plane = (j >> 8) & 1;
      const int rs = j >> 9;
      const u16* s = wpk + (((long)rs * ICB + icb) * 128 + oc0 + oc) * 32
                   + i8 * 8 + (plane ? WTOT : 0);
      const int didx = (rs * 2 + plane) * 2048 + ((oc * 32 + i8 * 8) ^ ((oc & 7) << 3));
      *reinterpret_cast<uint4*>(&smem[didx]) = *reinterpret_cast<const uint4*>(s);
    }
    __syncthreads();

    const u16* prh[3];
    const u16* prl[3];
    #pragma unroll
    for (int r = 0; r < 3; ++r) {
      const long rb = ((((long)b * H2 + h0 + r) * ICB + icb) * W2 + w0) * 32 + lane_b_off;
      prh[r] = in_hi + rb;
      prl[r] = in_lo + rb;
    }

    #pragma unroll
    for (int rs = 0; rs < 9; ++rs) {
      const int r = rs / 3, s = rs % 3;
      bf16x8 bhi[NF], blo[NF];
      #pragma unroll
      for (int nf = 0; nf < NF; ++nf) {
        bhi[nf] = *reinterpret_cast<const bf16x8*>(prh[r] + (nf * 16 + s) * 32);
        blo[nf] = *reinterpret_cast<const bf16x8*>(prl[r] + (nf * 16 + s) * 32);
      }
      #pragma unroll
      for (int mf = 0; mf < 4; ++mf) {
        const int ocl = mf * 16 + lm;
        const int aoff = rs * 4096 + ((ocl * 32 + lq * 8) ^ ((ocl & 7) << 3));
        bf16x8 ahi = *reinterpret_cast<const bf16x8*>(&smem[aoff]);
        bf16x8 alo = *reinterpret_cast<const bf16x8*>(&smem[aoff + 2048]);
        #pragma unroll
        for (int nf = 0; nf < NF; ++nf) {
          acc[mf][nf] = MFMA16(ahi, bhi[nf], acc[mf][nf]);
          acc[mf][nf] = MFMA16(ahi, blo[nf], acc[mf][nf]);
          acc[mf][nf] = MFMA16(alo, bhi[nf], acc[mf][nf]);
        }
      }
    }
  }

  __syncthreads();   // done with weights; overlay epilogue staging
  if (OUTPAD == 0) {
    float* lds_f = reinterpret_cast<float*>(smem);     // [PXB][64]
    #pragma unroll
    for (int mf = 0; mf < 4; ++mf)
      #pragma unroll
      for (int nf = 0; nf < NF; ++nf)
        #pragma unroll
        for (int reg = 0; reg < 4; ++reg) {
          const int px = wbase + nf * 16 + lm;
          const int ocl = mf * 16 + lq * 4 + reg;
          float v = acc[mf][nf][reg] + bias[oc0 + ocl];
          if (relu) v = fmaxf(v, 0.f);
          lds_f[px * 64 + ocl] = v;
        }
    __syncthreads();
    for (int i = tid; i < PXB * 16; i += 256) {
      const int px = i >> 4, og = (i & 15) * 4;
      *reinterpret_cast<float4*>(
          &outf[(((long)b * IH + h0) * IW + w0 + px) * 128 + oc0 + og]) =
          *reinterpret_cast<const float4*>(&lds_f[px * 64 + og]);
    }
  } else {
    u16* lh = smem;                    // [PXB][64]
    u16* ll = smem + PXB * 64;
    #pragma unroll
    for (int mf = 0; mf < 4; ++mf)
      #pragma unroll
      for (int nf = 0; nf < NF; ++nf)
        #pragma unroll
        for (int reg = 0; reg < 4; ++reg) {
          const int px = wbase + nf * 16 + lm;
          const int ocl = mf * 16 + lq * 4 + reg;
          float v = acc[mf][nf][reg] + bias[oc0 + ocl];
          if (relu) v = fmaxf(v, 0.f);
          u16 hh, l2;
          cvt_hilo(v, hh, l2);
          lh[px * 64 + ocl] = hh;
          ll[px * 64 + ocl] = l2;
        }
    __syncthreads();
    constexpr int H2o = IH + 2, W2o = IW + 2;
    for (int c = tid; c < PXB * 8; c += 256) {
      const int px = c >> 3, r8 = c & 7;
      const int icb2 = (oc0 >> 5) + (r8 >> 2);
      const int icl0 = (r8 & 3) * 8;
      const long ga = ((((long)b * H2o + h0 + 1) * 4 + icb2) * W2o + (w0 + px + 1)) * 32 + icl0;
      *reinterpret_cast<uint4*>(&out_hi[ga]) =
          *reinterpret_cast<const uint4*>(&lh[px * 64 + r8 * 8]);
      *reinterpret_cast<uint4*>(&out_lo[ga]) =
          *reinterpret_cast<const uint4*>(&ll[px * 64 + r8 * 8]);
    }
  }
}

// Attention: one block per (b, n). 128 threads.
__global__ __launch_bounds__(128) void attn_k(
    const float* __restrict__ q_cl, const float* __restrict__ k_cl,
    const float* __restrict__ z_cl, const int* __restrict__ u,
    float* __restrict__ out)
{
  constexpr float SCALE = 0.08838834764831845f;  // 128^-0.5
  const int n = blockIdx.x, b = blockIdx.y;
  const int t = threadIdx.x;

  __shared__ float qs[128];
  __shared__ float logit[32];
  __shared__ float el[32];

  int widx = u[b * 4096 + n];
  widx = widx < 0 ? 0 : (widx > 511 ? 511 : widx);

  qs[t] = q_cl[((long)b * 4096 + n) * 128 + t];
  __syncthreads();

  const int h = t >> 2, quad = t & 3;
  const float* kcol = k_cl + (((long)b * 32 + h) * 512 + widx) * 128 + quad * 32;
  float p = 0.f;
  #pragma unroll
  for (int j = 0; j < 32; j += 4) {
    const float4 kv = *reinterpret_cast<const float4*>(kcol + j);
    p = fmaf(qs[quad * 32 + j + 0], kv.x, p);
    p = fmaf(qs[quad * 32 + j + 1], kv.y, p);
    p = fmaf(qs[quad * 32 + j + 2], kv.z, p);
    p = fmaf(qs[quad * 32 + j + 3], kv.w, p);
  }
  p += __shfl_xor(p, 1);
  p += __shfl_xor(p, 2);
  if (quad == 0) logit[h] = p * SCALE;
  __syncthreads();

  float m = -3.4e38f;
  #pragma unroll
  for (int h2 = 0; h2 < 32; ++h2) m = fmaxf(m, logit[h2]);
  if (t < 32) el[t] = __expf(logit[t] - m);
  __syncthreads();
  float den = 0.f;
  #pragma unroll
  for (int h2 = 0; h2 < 32; ++h2) den += el[h2];

  const float* zcol = z_cl + ((long)b * 32 * 512 + widx) * 128 + t;
  float o = 0.f;
  #pragma unroll
  for (int h2 = 0; h2 < 32; ++h2) o = fmaf(el[h2], zcol[(long)h2 * 512 * 128], o);
  out[((long)b * 4096 + n) * 128 + t] = o / den;
}

extern "C" void kernel_launch(void* const* d_in, const int* in_sizes, int n_in,
                              void* d_out, int out_size, void* d_ws, size_t ws_size,
                              hipStream_t stream) {
  const float* x   = (const float*)d_in[0];
  const float* y   = (const float*)d_in[1];
  const float* z   = (const float*)d_in[2];
  const int*   u   = (const int*)  d_in[3];
  const float* wq1 = (const float*)d_in[4];
  const float* bq1 = (const float*)d_in[5];
  const float* wq2 = (const float*)d_in[6];
  const float* bq2 = (const float*)d_in[7];
  const float* wk1 = (const float*)d_in[8];
  const float* bk1 = (const float*)d_in[9];
  const float* wk2 = (const float*)d_in[10];
  const float* bk2 = (const float*)d_in[11];
  float* out = (float*)d_out;
  u16* wsu = (u16*)d_ws;

  // ---- arena (u16 offsets), overlaid by lifetime; total 74.0 MB
  // ypad [2][34][8][514][32] x2 planes : 0 .. 17,895,424   (dead after convk1)
  u16* ypad_hi = wsu + 0;
  u16* ypad_lo = wsu + 8947712;
  //   xpad [2][66][8][66][32] x2 overlays ypad
  u16* xpad_hi = wsu + 0;
  u16* xpad_lo = wsu + 2230272;
  //   t1q [2][66][4][66][32] x2 after xpad
  u16* t1q_hi = wsu + 4460544;
  u16* t1q_lo = wsu + 5575680;
  //   q_cl fp32 [2,4096,128] after t1q
  float* q_cl = (float*)(wsu + 6690816);
  // t2k [2][34][4][514][32] x2 : 17,895,424 .. 26,843,136  (dead after convk2)
  u16* t2k_hi = wsu + 17895424;
  u16* t2k_lo = wsu + 22369280;
  //   z_cl fp32 [2,32,512,128] overlays t2k
  float* z_cl = (float*)(wsu + 17895424);
  // k_cl fp32 [2,32,512,128] : 26,843,136 ..
  float* k_cl = (float*)(wsu + 26843136);
  // packed weights : 35,231,744 ..
  u16* wpk_q1 = wsu + 35231744;   // 589,824
  u16* wpk_q2 = wsu + 35821568;   // 294,912
  u16* wpk_k1 = wsu + 36116480;   // 589,824
  u16* wpk_k2 = wsu + 36706304;   // 294,912 -> end 37,001,216 u16 = 74.0 MB

  // ---- weight packing
  pack_w_k<<<dim3(128), 256, 0, stream>>>(wq1, wpk_q1, 256);
  pack_w_k<<<dim3(64),  256, 0, stream>>>(wq2, wpk_q2, 128);
  pack_w_k<<<dim3(128), 256, 0, stream>>>(wk1, wpk_k1, 256);
  pack_w_k<<<dim3(64),  256, 0, stream>>>(wk2, wpk_k2, 128);

  // ---- k path
  {  // zero halos: ypad (H2=34,ICB=8,W2=514), t2k (ICB=4)
    long ry = 2L*8*2*514*32 + 2L*8*32*2*32;    // 591,872
    long rt = 2L*4*2*514*32 + 2L*4*32*2*32;    // 295,936
    zero_halo_k<<<dim3((ry + 255) / 256), 256, 0, stream>>>(ypad_hi, 34, 8, 514);
    zero_halo_k<<<dim3((ry + 255) / 256), 256, 0, stream>>>(ypad_lo, 34, 8, 514);
    zero_halo_k<<<dim3((rt + 255) / 256), 256, 0, stream>>>(t2k_hi, 34, 4, 514);
    zero_halo_k<<<dim3((rt + 255) / 256), 256, 0, stream>>>(t2k_lo, 34, 4, 514);
  }
  cvt_pad_k<<<dim3(16, 8, 64), dim3(32, 8), 0, stream>>>(y, ypad_hi, ypad_lo, 256, 32, 512);
  conv3x3_mfma_k<256, 32, 512, 128, 1><<<dim3(4, 32, 4), 256, 0, stream>>>(
      ypad_hi, ypad_lo, wpk_k1, bk1, nullptr, t2k_hi, t2k_lo, 1);
  conv3x3_mfma_k<128, 32, 512, 128, 0><<<dim3(4, 32, 4), 256, 0, stream>>>(
      t2k_hi, t2k_lo, wpk_k2, bk2, k_cl, nullptr, nullptr, 0);

  // ---- v path (z -> channels-last; overlays dead t2k)
  transpose_cl_k<<<dim3(16, 4, 64), dim3(32, 8), 0, stream>>>(z, z_cl, 128, 32, 512);

  // ---- q path (overlays dead ypad)
  {  // zero halos: xpad (H2=66,ICB=8,W2=66), t1q (ICB=4)
    long rx = 2L*8*2*66*32 + 2L*8*64*2*32;     // 266,240
    long rq = 2L*4*2*66*32 + 2L*4*64*2*32;     // 133,120
    zero_halo_k<<<dim3((rx + 255) / 256), 256, 0, stream>>>(xpad_hi, 66, 8, 66);
    zero_halo_k<<<dim3((rx + 255) / 256), 256, 0, stream>>>(xpad_lo, 66, 8, 66);
    zero_halo_k<<<dim3((rq + 255) / 256), 256, 0, stream>>>(t1q_hi, 66, 4, 66);
    zero_halo_k<<<dim3((rq + 255) / 256), 256, 0, stream>>>(t1q_lo, 66, 4, 66);
  }
  cvt_pad_k<<<dim3(2, 8, 128), dim3(32, 8), 0, stream>>>(x, xpad_hi, xpad_lo, 256, 64, 64);
  conv3x3_mfma_k<256, 64, 64, 64, 1><<<dim3(1, 64, 4), 256, 0, stream>>>(
      xpad_hi, xpad_lo, wpk_q1, bq1, nullptr, t1q_hi, t1q_lo, 1);
  conv3x3_mfma_k<128, 64, 64, 64, 0><<<dim3(1, 64, 4), 256, 0, stream>>>(
      t1q_hi, t1q_lo, wpk_q2, bq2, q_cl, nullptr, nullptr, 0);

  // ---- fused gather + attention
  attn_k<<<dim3(4096, 2), 128, 0, stream>>>(q_cl, k_cl, z_cl, u, out);
}

// Round 5
// 189.394 us; speedup vs baseline: 4.0022x; 1.1840x over previous
//
#include <hip/hip_runtime.h>

// ---------------------------------------------------------------------------
// x [2,256,64,64]  y [2,256,32,512]  z [2,128,32,512]  u [2,64,64] int
// wq1/wk1 [128,256,3,3]  wq2/wk2 [128,128,3,3]  biases [128]   out [2,4096,128]
//
// f16 2-term MFMA convs: weights split exactly into f16 hi+lo planes
// (error = activation f16 rounding only); activations single f16 plane,
// channels-last-blocked [B][H][C/32][W][32] (bounds-checked, no padding).
// Conv: 4-wave blocks, wave = 2 rows x 32 px x 64 oc; B-frags register-cached
// per 32-ic chunk (24 loads), weights LDS-staged (XOR-swizzled, 9 shifts);
// per rs-step: 8 ds_read_b128 + 32 MFMA, zero B loads, 2 barriers/chunk.
// 5 launches total: pack, cvt, conv1(q+k merged), conv2(q+k merged), attn.
// ---------------------------------------------------------------------------

typedef __attribute__((ext_vector_type(8))) _Float16 f16x8;
typedef __attribute__((ext_vector_type(4))) float f32x4;
typedef __attribute__((ext_vector_type(8))) unsigned short us8;
typedef unsigned short u16;

#define MFMA16F(A, B, C) __builtin_amdgcn_mfma_f32_16x16x32_f16((A), (B), (C), 0, 0, 0)

// ---- pack all 4 weight tensors: [128][IC][3][3] f32 -> f16 hi plane
// [9][IC/32][128][32] + f16 lo plane at +9*(IC/32)*128*32. 384 blocks.
__global__ __launch_bounds__(256) void pack_all_k(
    const float* __restrict__ wq1, const float* __restrict__ wq2,
    const float* __restrict__ wk1, const float* __restrict__ wk2,
    u16* __restrict__ pq1, u16* __restrict__ pq2,
    u16* __restrict__ pk1, u16* __restrict__ pk2)
{
  int t = blockIdx.x * 256 + threadIdx.x;
  const float* w; u16* dst; int IC, tt;
  if (t < 32768)      { w = wq1; dst = pq1; IC = 256; tt = t; }
  else if (t < 49152) { w = wq2; dst = pq2; IC = 128; tt = t - 32768; }
  else if (t < 81920) { w = wk1; dst = pk1; IC = 256; tt = t - 49152; }
  else                { w = wk2; dst = pk2; IC = 128; tt = t - 81920; }
  int oc = tt / IC, ic = tt % IC;
  int ICB = IC >> 5;
  int WTOT = 9 * ICB * 128 * 32;
  #pragma unroll
  for (int rs = 0; rs < 9; ++rs) {
    float v = w[(oc * IC + ic) * 9 + rs];
    _Float16 hi = (_Float16)v;
    _Float16 lo = (_Float16)(v - (float)hi);
    int idx = ((rs * ICB + (ic >> 5)) * 128 + oc) * 32 + (ic & 31);
    dst[idx] = __builtin_bit_cast(u16, hi);
    dst[WTOT + idx] = __builtin_bit_cast(u16, lo);
  }
}

// ---- one merged transpose/cvt kernel:
//  y -> ycl f16 [2][32][8][512][32], x -> xcl f16 [2][64][8][64][32],
//  z -> zcl f32 [2][32][512][128].  14336 blocks of (32,8).
__global__ void cvt_all_k(const float* __restrict__ x, const float* __restrict__ y,
                          const float* __restrict__ z,
                          u16* __restrict__ xcl, u16* __restrict__ ycl,
                          float* __restrict__ zcl)
{
  __shared__ float tile[32][33];
  const int id = blockIdx.x;
  const float* src; int C, H, W, wt, cb, bh, mode;
  u16* d16 = nullptr; float* d32 = nullptr;
  if (id < 8192)       { src = y; C = 256; H = 32; W = 512; wt = id & 15;        cb = (id >> 4) & 7; bh = id >> 7; d16 = ycl; mode = 0; }
  else if (id < 10240) { int i2 = id - 8192;  src = x; C = 256; H = 64; W = 64;  wt = i2 & 1;  cb = (i2 >> 1) & 7; bh = i2 >> 4; d16 = xcl; mode = 0; }
  else                 { int i3 = id - 10240; src = z; C = 128; H = 32; W = 512; wt = i3 & 15; cb = (i3 >> 4) & 3; bh = i3 >> 6; d32 = zcl; mode = 1; }
  const int b = bh / H, h = bh % H;
  const int w0 = wt * 32;
  const int tx = threadIdx.x, ty = threadIdx.y;
  #pragma unroll
  for (int k2 = 0; k2 < 4; ++k2) {
    int c = cb * 32 + ty + k2 * 8;
    tile[ty + k2 * 8][tx] = src[(((long)b * C + c) * H + h) * W + w0 + tx];
  }
  __syncthreads();
  if (mode == 0) {
    // thread j owns channel-pair cp and pixel wl; 2 pixel halves.
    const int ICB = C >> 5;
    const int j = ty * 32 + tx;
    const int cp = (j & 15) * 2;
    const int wl = j >> 4;
    #pragma unroll
    for (int half = 0; half < 2; ++half) {
      const int wloc = wl + half * 16;
      unsigned int lo = (unsigned int)__builtin_bit_cast(u16, (_Float16)tile[cp][wloc]);
      unsigned int hi = (unsigned int)__builtin_bit_cast(u16, (_Float16)tile[cp + 1][wloc]);
      long idx = ((((long)b * H + h) * ICB + cb) * W + (w0 + wloc)) * 32 + cp;
      *reinterpret_cast<unsigned int*>(&d16[idx]) = lo | (hi << 16);
    }
  } else {
    #pragma unroll
    for (int k2 = 0; k2 < 4; ++k2) {
      int w = w0 + ty + k2 * 8;
      d32[(((long)b * H + h) * W + w) * 128 + cb * 32 + tx] = tile[tx][ty + k2 * 8];
    }
  }
}

// ---- merged conv (k-path blocks [0,256) + q-path blocks [256,320)).
// Per block: 64 oc x rows_pb rows x pxspan px. Wave: 2 rows x 32 px.
// OF16=1: f16 out [B][IH][4][IW][32] + relu. OF16=0: f32 out [B][IH][IW][128].
template<int ICB, int OF16>
__global__ __launch_bounds__(256, 2) void conv_merged_k(
    const u16* __restrict__ inK, const u16* __restrict__ wpkK,
    const float* __restrict__ biasK, void* __restrict__ outK,
    const u16* __restrict__ inQ, const u16* __restrict__ wpkQ,
    const float* __restrict__ biasQ, void* __restrict__ outQ)
{
  constexpr int WTOT = 9 * ICB * 128 * 32;
  __shared__ __align__(16) u16 smem[9 * 2 * 2048];   // 73728 B

  const int tid = threadIdx.x;
  const int lane = tid & 63, wv = tid >> 6;
  const int lm = lane & 15, lq = lane >> 4;
  const int bid = blockIdx.x;

  const u16* in; const u16* wpk; const float* bias; void* outp;
  int IH, IW, pxspan, rows_pb, wpr, w0, hb, z;
  if (bid < 256) {
    in = inK; wpk = wpkK; bias = biasK; outp = outK;
    IH = 32; IW = 512; pxspan = 128; rows_pb = 2; wpr = 4;
    w0 = (bid & 3) * 128; hb = ((bid >> 2) & 15) * 2; z = bid >> 6;
  } else {
    int qb = bid - 256;
    in = inQ; wpk = wpkQ; bias = biasQ; outp = outQ;
    IH = 64; IW = 64; pxspan = 64; rows_pb = 4; wpr = 2;
    w0 = 0; hb = (qb & 15) * 4; z = qb >> 4;
  }
  const int b = z >> 1, oc0 = (z & 1) * 64;
  const int rp = wv / wpr;
  const int pxw = (wv % wpr) * 32;
  const int hw0 = hb + rp * 2;

  f32x4 acc[4][2][2];
  #pragma unroll
  for (int mf = 0; mf < 4; ++mf)
    #pragma unroll
    for (int jj = 0; jj < 2; ++jj)
      #pragma unroll
      for (int f = 0; f < 2; ++f) acc[mf][jj][f] = (f32x4)0.f;

  for (int icb = 0; icb < ICB; ++icb) {
    // ---- B fragments -> registers (issued before barrier: overlap staging)
    f16x8 braw[4][6];
    #pragma unroll
    for (int jr = 0; jr < 4; ++jr) {
      const int ri = hw0 - 1 + jr;
      const bool rv = (unsigned)ri < (unsigned)IH;
      const u16* rowp = in + ((((long)b * IH + (rv ? ri : 0)) * ICB + icb) * (long)IW) * 32 + lq * 8;
      #pragma unroll
      for (int c = 0; c < 6; ++c) {
        const int px = w0 + pxw + (c / 3) * 16 + (c % 3) - 1 + lm;
        us8 v = {0, 0, 0, 0, 0, 0, 0, 0};
        if (rv && (unsigned)px < (unsigned)IW)
          v = *reinterpret_cast<const us8*>(rowp + (long)px * 32);
        braw[jr][c] = __builtin_bit_cast(f16x8, v);
      }
    }

    __syncthreads();   // prior iter done reading smem
    // ---- stage 9 shifts' 64x32 hi+lo f16 weight tiles (XOR-swizzled)
    #pragma unroll
    for (int j0 = 0; j0 < 18; ++j0) {
      const int j = j0 * 256 + tid;
      const int i8 = j & 3, oc = (j >> 2) & 63, plane = (j >> 8) & 1, rs = j >> 9;
      const u16* s = wpk + (((long)rs * ICB + icb) * 128 + oc0 + oc) * 32
                   + i8 * 8 + (plane ? WTOT : 0);
      const int didx = (rs * 2 + plane) * 2048 + ((oc * 32 + i8 * 8) ^ ((oc & 7) << 3));
      *reinterpret_cast<uint4*>(&smem[didx]) = *reinterpret_cast<const uint4*>(s);
    }
    __syncthreads();

    #pragma unroll
    for (int r = 0; r < 3; ++r)
      #pragma unroll
      for (int s = 0; s < 3; ++s) {
        const int rs = r * 3 + s;
        #pragma unroll
        for (int mf = 0; mf < 4; ++mf) {
          const int ocl = mf * 16 + lm;
          const int aoff = rs * 4096 + ((ocl * 32 + lq * 8) ^ ((ocl & 7) << 3));
          f16x8 ahi = *reinterpret_cast<const f16x8*>(&smem[aoff]);
          f16x8 alo = *reinterpret_cast<const f16x8*>(&smem[aoff + 2048]);
          #pragma unroll
          for (int jj = 0; jj < 2; ++jj)
            #pragma unroll
            for (int f = 0; f < 2; ++f) {
              f16x8 bb = braw[jj + r][f * 3 + s];
              acc[mf][jj][f] = MFMA16F(ahi, bb, acc[mf][jj][f]);
              acc[mf][jj][f] = MFMA16F(alo, bb, acc[mf][jj][f]);
            }
        }
      }
  }

  // ---- epilogue (swizzled LDS staging; conflict-free)
  __syncthreads();
  if (OF16) {
    u16* st = smem;   // [rows_pb][pxspan][64] u16
    #pragma unroll
    for (int mf = 0; mf < 4; ++mf)
      #pragma unroll
      for (int jj = 0; jj < 2; ++jj)
        #pragma unroll
        for (int f = 0; f < 2; ++f)
          #pragma unroll
          for (int reg = 0; reg < 4; ++reg) {
            const int ocl = mf * 16 + lq * 4 + reg;
            const int px = pxw + f * 16 + lm;
            const int row = rp * 2 + jj;
            float v = fmaxf(acc[mf][jj][f][reg] + bias[oc0 + ocl], 0.f);  // relu
            st[(row * pxspan + px) * 64 + (ocl ^ ((px & 7) << 3))] =
                __builtin_bit_cast(u16, (_Float16)v);
          }
    __syncthreads();
    u16* og = (u16*)outp;
    const int nch = rows_pb * pxspan * 8;
    for (int i = tid; i < nch; i += 256) {
      const int cir = i % (pxspan * 8), row = i / (pxspan * 8);
      const int px = cir >> 3, o8 = cir & 7;
      const int icb2 = (oc0 >> 5) + (o8 >> 2), icl = (o8 & 3) * 8;
      const long didx = ((((long)b * IH + hb + row) * 4 + icb2) * (long)IW + (w0 + px)) * 32 + icl;
      us8 val = *reinterpret_cast<const us8*>(
          &st[(row * pxspan + px) * 64 + ((o8 * 8) ^ ((px & 7) << 3))]);
      *reinterpret_cast<us8*>(&og[didx]) = val;
    }
  } else {
    float* st = reinterpret_cast<float*>(smem);   // [rows_pb][pxspan][64] f32
    #pragma unroll
    for (int mf = 0; mf < 4; ++mf)
      #pragma unroll
      for (int jj = 0; jj < 2; ++jj)
        #pragma unroll
        for (int f = 0; f < 2; ++f)
          #pragma unroll
          for (int reg = 0; reg < 4; ++reg) {
            const int ocl = mf * 16 + lq * 4 + reg;
            const int px = pxw + f * 16 + lm;
            const int row = rp * 2 + jj;
            st[(row * pxspan + px) * 64 + (ocl ^ ((px & 7) << 3))] =
                acc[mf][jj][f][reg] + bias[oc0 + ocl];
          }
    __syncthreads();
    float* og = (float*)outp;
    const int nch = rows_pb * pxspan * 16;
    for (int i = tid; i < nch; i += 256) {
      const int cir = i % (pxspan * 16), row = i / (pxspan * 16);
      const int px = cir >> 4, o4 = cir & 15;
      const long didx = (((long)b * IH + hb + row) * (long)IW + (w0 + px)) * 128 + oc0 + o4 * 4;
      float4 val = *reinterpret_cast<const float4*>(
          &st[(row * pxspan + px) * 64 + ((o4 * 4) ^ ((px & 7) << 3))]);
      *reinterpret_cast<float4*>(&og[didx]) = val;
    }
  }
}

// ---- attention: one block per (b, n). 128 threads.
// q_cl [B,4096,128] f32, k_cl [B,32,512,128] f32, zcl [B,32,512,128] f32.
__global__ __launch_bounds__(128) void attn_k(
    const float* __restrict__ q_cl, const float* __restrict__ k_cl,
    const float* __restrict__ zcl, const int* __restrict__ u,
    float* __restrict__ out)
{
  constexpr float SCALE = 0.08838834764831845f;  // 128^-0.5
  const int n = blockIdx.x, b = blockIdx.y;
  const int t = threadIdx.x;

  __shared__ float qs[128];
  __shared__ float logit[32];
  __shared__ float el[32];

  int widx = u[b * 4096 + n];
  widx = widx < 0 ? 0 : (widx > 511 ? 511 : widx);

  qs[t] = q_cl[((long)b * 4096 + n) * 128 + t];
  __syncthreads();

  const int h = t >> 2, quad = t & 3;
  const float* kcol = k_cl + (((long)b * 32 + h) * 512 + widx) * 128 + quad * 32;
  float p = 0.f;
  #pragma unroll
  for (int j = 0; j < 32; j += 4) {
    const float4 kv = *reinterpret_cast<const float4*>(kcol + j);
    p = fmaf(qs[quad * 32 + j + 0], kv.x, p);
    p = fmaf(qs[quad * 32 + j + 1], kv.y, p);
    p = fmaf(qs[quad * 32 + j + 2], kv.z, p);
    p = fmaf(qs[quad * 32 + j + 3], kv.w, p);
  }
  p += __shfl_xor(p, 1);
  p += __shfl_xor(p, 2);
  if (quad == 0) logit[h] = p * SCALE;
  __syncthreads();

  float m = -3.4e38f;
  #pragma unroll
  for (int h2 = 0; h2 < 32; ++h2) m = fmaxf(m, logit[h2]);
  if (t < 32) el[t] = __expf(logit[t] - m);
  __syncthreads();
  float den = 0.f;
  #pragma unroll
  for (int h2 = 0; h2 < 32; ++h2) den += el[h2];

  const float* zcol = zcl + ((long)b * 32 * 512 + widx) * 128 + t;
  float o0 = 0.f, o1 = 0.f, o2 = 0.f, o3 = 0.f;
  #pragma unroll
  for (int h2 = 0; h2 < 32; h2 += 4) {
    o0 = fmaf(el[h2 + 0], zcol[(long)(h2 + 0) * 512 * 128], o0);
    o1 = fmaf(el[h2 + 1], zcol[(long)(h2 + 1) * 512 * 128], o1);
    o2 = fmaf(el[h2 + 2], zcol[(long)(h2 + 2) * 512 * 128], o2);
    o3 = fmaf(el[h2 + 3], zcol[(long)(h2 + 3) * 512 * 128], o3);
  }
  out[((long)b * 4096 + n) * 128 + t] = ((o0 + o1) + (o2 + o3)) / den;
}

extern "C" void kernel_launch(void* const* d_in, const int* in_sizes, int n_in,
                              void* d_out, int out_size, void* d_ws, size_t ws_size,
                              hipStream_t stream) {
  const float* x   = (const float*)d_in[0];
  const float* y   = (const float*)d_in[1];
  const float* z   = (const float*)d_in[2];
  const int*   u   = (const int*)  d_in[3];
  const float* wq1 = (const float*)d_in[4];
  const float* bq1 = (const float*)d_in[5];
  const float* wq2 = (const float*)d_in[6];
  const float* bq2 = (const float*)d_in[7];
  const float* wk1 = (const float*)d_in[8];
  const float* bk1 = (const float*)d_in[9];
  const float* wk2 = (const float*)d_in[10];
  const float* bk2 = (const float*)d_in[11];
  float* out = (float*)d_out;
  u16* wsu = (u16*)d_ws;

  // ---- arena (u16 offsets); total 72.7 MB
  u16*   ycl  = wsu + 0;           //  8,388,608  [2][32][8][512][32] f16
  u16*   xcl  = wsu + 8388608;     //  2,097,152  [2][64][8][64][32]  f16
  float* zcl  = (float*)(wsu + 10485760);  // 4,194,304 f32 [2][32][512][128]
  u16*   t2k  = wsu + 18874368;    //  4,194,304  [2][32][4][512][32] f16
  u16*   t1q  = wsu + 23068672;    //  1,048,576  [2][64][4][64][32]  f16
  float* k_cl = (float*)(wsu + 24117248);  // 4,194,304 f32 [2][32][512][128]
  float* q_cl = (float*)(wsu + 32505856);  // 1,048,576 f32 [2,4096,128]
  u16* wpk_q1 = wsu + 34603008;    //    589,824 (hi+lo)
  u16* wpk_q2 = wsu + 35192832;    //    294,912
  u16* wpk_k1 = wsu + 35487744;    //    589,824
  u16* wpk_k2 = wsu + 36077568;    //    294,912  -> end 36,372,480 u16

  pack_all_k<<<dim3(384), 256, 0, stream>>>(wq1, wq2, wk1, wk2,
                                            wpk_q1, wpk_q2, wpk_k1, wpk_k2);
  cvt_all_k<<<dim3(14336), dim3(32, 8), 0, stream>>>(x, y, z, xcl, ycl, zcl);
  conv_merged_k<8, 1><<<dim3(320), 256, 0, stream>>>(
      ycl, wpk_k1, bk1, (void*)t2k, xcl, wpk_q1, bq1, (void*)t1q);
  conv_merged_k<4, 0><<<dim3(320), 256, 0, stream>>>(
      t2k, wpk_k2, bk2, (void*)k_cl, t1q, wpk_q2, bq2, (void*)q_cl);
  attn_k<<<dim3(4096, 2), 128, 0, stream>>>(q_cl, k_cl, zcl, u, out);
}

// Round 6
// 134.929 us; speedup vs baseline: 5.6178x; 1.4037x over previous
//
#include <hip/hip_runtime.h>

// ---------------------------------------------------------------------------
// x [2,256,64,64]  y [2,256,32,512]  z [2,128,32,512]  u [2,64,64] int
// wq1/wk1 [128,256,3,3]  wq2/wk2 [128,128,3,3]  biases [128]   out [2,4096,128]
//
// f16 2-term MFMA convs (weights = exact f16 hi+lo split; activations f16).
// Activations in halo-padded layout [B][H+2][IC/32][W+2][32] f16 (zero halos,
// no bounds checks). Conv blocks: 32 oc x (2 rows x 128 px | 4 rows x 64 px),
// 4 waves, wave = 2 rows x 32 px. Weights LDS-staged pre-swizzled (36.9 KB ->
// 4 blocks/CU); B-frags per-rs direct from global (coalesced 1KB, L1/L2-hot).
// Grid 640 uniform blocks, all co-resident. 5 launches.
// ---------------------------------------------------------------------------

typedef __attribute__((ext_vector_type(8))) _Float16 f16x8;
typedef __attribute__((ext_vector_type(4))) float f32x4;
typedef __attribute__((ext_vector_type(8))) unsigned short us8;
typedef unsigned short u16;

#define MFMA16F(A, B, C) __builtin_amdgcn_mfma_f32_16x16x32_f16((A), (B), (C), 0, 0, 0)

// Weight layout (pre-swizzled): flat(rs,icb,pl,ocq,j) =
//   rs*(ICB*8192) + icb*8192 + pl*4096 + ocq*1024 + j,
// j = ((ocl*32 + ic) ^ ((ocl&7)<<3)), ocl in [0,32), ic in [0,32).  (bijective)
// Activation layout: FL(b,hp,icb,wp,c) = (((b*H2+hp)*ICB+icb)*W2+wp)*32 + c.

// ---- pack weights (384 blocks) + zero activation halos (127 blocks)
__global__ __launch_bounds__(256) void pack_zero_k(
    const float* __restrict__ wq1, const float* __restrict__ wq2,
    const float* __restrict__ wk1, const float* __restrict__ wk2,
    u16* __restrict__ pq1, u16* __restrict__ pq2,
    u16* __restrict__ pk1, u16* __restrict__ pk2,
    u16* __restrict__ ypad, u16* __restrict__ xpad,
    u16* __restrict__ t2k, u16* __restrict__ t1q)
{
  const int bid = blockIdx.x;
  if (bid < 384) {
    int t = bid * 256 + threadIdx.x;
    const float* w; u16* dst; int IC, tt;
    if (t < 32768)      { w = wq1; dst = pq1; IC = 256; tt = t; }
    else if (t < 49152) { w = wq2; dst = pq2; IC = 128; tt = t - 32768; }
    else if (t < 81920) { w = wk1; dst = pk1; IC = 256; tt = t - 49152; }
    else                { w = wk2; dst = pk2; IC = 128; tt = t - 81920; }
    const int oc = tt / IC, ic = tt % IC;
    const int ICB = IC >> 5;
    const int swz = (((oc & 31) << 5) | (ic & 31)) ^ ((oc & 7) << 3);
    #pragma unroll
    for (int rs = 0; rs < 9; ++rs) {
      float v = w[(oc * IC + ic) * 9 + rs];
      _Float16 hi = (_Float16)v;
      _Float16 lo = (_Float16)(v - (float)hi);
      long base = (long)rs * (ICB * 8192) + (long)(ic >> 5) * 8192
                + (long)(oc >> 5) * 1024 + swz;
      dst[base] = __builtin_bit_cast(u16, hi);
      dst[base + 4096] = __builtin_bit_cast(u16, lo);
    }
  } else {
    // zero halos: units of 32 u16 (64 B). totals: ypad 17472, xpad 4160,
    // t2k 8736, t1q 2080 -> cum 17472, 21632, 30368, 32448.
    long u = (long)(bid - 384) * 256 + threadIdx.x;
    if (u >= 32448) return;
    u16* p; int ICB, H, W2;
    if (u < 17472)      { p = ypad; ICB = 8; H = 32; W2 = 514; }
    else if (u < 21632) { u -= 17472; p = xpad; ICB = 8; H = 64; W2 = 66; }
    else if (u < 30368) { u -= 21632; p = t2k; ICB = 4; H = 32; W2 = 514; }
    else                { u -= 30368; p = t1q; ICB = 4; H = 64; W2 = 66; }
    const int H2 = H + 2;
    const long rowsN = (long)2 * ICB * 2 * W2;
    long base;
    if (u < rowsN) {
      int w = (int)(u % W2);
      int t2 = (int)(u / W2);
      int tb = t2 & 1, icb = (t2 >> 1) % ICB, b = (t2 >> 1) / ICB;
      int h = tb ? H2 - 1 : 0;
      base = ((((long)b * H2 + h) * ICB + icb) * W2 + w) * 32;
    } else {
      long v = u - rowsN;
      int side = (int)(v & 1);
      long v2 = v >> 1;
      int h = 1 + (int)(v2 % H);
      int icb = (int)((v2 / H) % ICB);
      int b = (int)(v2 / ((long)H * ICB));
      int w = side ? W2 - 1 : 0;
      base = ((((long)b * H2 + h) * ICB + icb) * W2 + w) * 32;
    }
    us8 zz = {0, 0, 0, 0, 0, 0, 0, 0};
    #pragma unroll
    for (int j = 0; j < 4; ++j)
      *reinterpret_cast<us8*>(&p[base + j * 8]) = zz;
  }
}

// ---- merged transpose/cvt: y -> ypad f16 [2][34][8][514][32] (interior),
// x -> xpad f16 [2][66][8][66][32], z -> zcl f32 [2][32][512][128].
__global__ void cvt_all_k(const float* __restrict__ x, const float* __restrict__ y,
                          const float* __restrict__ z,
                          u16* __restrict__ xpad, u16* __restrict__ ypad,
                          float* __restrict__ zcl)
{
  __shared__ float tile[32][33];
  const int id = blockIdx.x;
  const float* src; int C, H, W, wt, cb, bh, mode, H2, W2;
  u16* d16 = nullptr; float* d32 = nullptr;
  if (id < 8192)       { src = y; C = 256; H = 32; W = 512; wt = id & 15;       cb = (id >> 4) & 7; bh = id >> 7; d16 = ypad; mode = 0; H2 = 34; W2 = 514; }
  else if (id < 10240) { int i2 = id - 8192;  src = x; C = 256; H = 64; W = 64; wt = i2 & 1;  cb = (i2 >> 1) & 7; bh = i2 >> 4; d16 = xpad; mode = 0; H2 = 66; W2 = 66; }
  else                 { int i3 = id - 10240; src = z; C = 128; H = 32; W = 512; wt = i3 & 15; cb = (i3 >> 4) & 3; bh = i3 >> 6; d32 = zcl; mode = 1; H2 = 0; W2 = 0; }
  const int b = bh / H, h = bh % H;
  const int w0 = wt * 32;
  const int tx = threadIdx.x, ty = threadIdx.y;
  #pragma unroll
  for (int k2 = 0; k2 < 4; ++k2) {
    int c = cb * 32 + ty + k2 * 8;
    tile[ty + k2 * 8][tx] = src[(((long)b * C + c) * H + h) * W + w0 + tx];
  }
  __syncthreads();
  if (mode == 0) {
    const int ICB = C >> 5;
    const int j = ty * 32 + tx;
    const int cp = (j & 15) * 2;
    const int wl = j >> 4;
    #pragma unroll
    for (int half = 0; half < 2; ++half) {
      const int wloc = wl + half * 16;
      unsigned int lo = (unsigned int)__builtin_bit_cast(u16, (_Float16)tile[cp][wloc]);
      unsigned int hi = (unsigned int)__builtin_bit_cast(u16, (_Float16)tile[cp + 1][wloc]);
      long idx = ((((long)b * H2 + h + 1) * ICB + cb) * W2 + (w0 + wloc + 1)) * 32 + cp;
      *reinterpret_cast<unsigned int*>(&d16[idx]) = lo | (hi << 16);
    }
  } else {
    #pragma unroll
    for (int k2 = 0; k2 < 4; ++k2) {
      int w = w0 + ty + k2 * 8;
      d32[(((long)b * H + h) * W + w) * 128 + cb * 32 + tx] = tile[tx][ty + k2 * 8];
    }
  }
}

// ---- merged conv (k blocks [0,512) + q blocks [512,640)).
// Block: 32 oc (ocq) x ROWS_PB rows x PXS px; wave = 2 rows x 32 px.
// OF16=1: f16 padded out [B][IH+2][4][IW+2][32] + relu.
// OF16=0: f32 out [B][IH][IW][128].
template<int ICB, int OF16>
__global__ __launch_bounds__(256, 3) void conv_k(
    const u16* __restrict__ inK, const u16* __restrict__ wpkK,
    const float* __restrict__ biasK, void* __restrict__ outK,
    const u16* __restrict__ inQ, const u16* __restrict__ wpkQ,
    const float* __restrict__ biasQ, void* __restrict__ outQ)
{
  __shared__ __align__(16) u16 smem[18432];   // 36864 B: 9 rs x 2 pl x 1024

  const int tid = threadIdx.x;
  const int lane = tid & 63, wv = tid >> 6;
  const int lm = lane & 15, lq = lane >> 4;
  const int bid = blockIdx.x;

  const u16* in; const u16* wpk; const float* bias; void* outp;
  int IH, IW, PXS, RPB, wpr, w0, hb, rest;
  if (bid < 512) {
    in = inK; wpk = wpkK; bias = biasK; outp = outK;
    IH = 32; IW = 512; PXS = 128; RPB = 2; wpr = 4;
    w0 = (bid & 3) * 128; hb = ((bid >> 2) & 15) * 2; rest = bid >> 6;
  } else {
    int qb = bid - 512;
    in = inQ; wpk = wpkQ; bias = biasQ; outp = outQ;
    IH = 64; IW = 64; PXS = 64; RPB = 4; wpr = 2;
    w0 = 0; hb = (qb & 15) * 4; rest = qb >> 4;
  }
  const int b = rest >> 2, ocq = rest & 3;
  const int H2 = IH + 2, W2 = IW + 2;
  const int rp = wv / wpr, pxw = (wv % wpr) * 32;
  const int hw0 = hb + rp * 2;

  // A-frag swizzled offsets (mf=0/1); (16+lm)&7 == lm&7 so mf=1 is +512.
  const int aswz0 = (lm * 32 + lq * 8) ^ ((lm & 7) << 3);
  const int aswz1 = aswz0 + 512;

  f32x4 acc[2][2][2];   // [mf][jj][f]
  #pragma unroll
  for (int mf = 0; mf < 2; ++mf)
    #pragma unroll
    for (int jj = 0; jj < 2; ++jj)
      #pragma unroll
      for (int f = 0; f < 2; ++f) acc[mf][jj][f] = (f32x4)0.f;

  for (int icb = 0; icb < ICB; ++icb) {
    __syncthreads();
    // ---- stage this icb's 9x2 pre-swizzled 32x32 weight tiles (linear copy)
    #pragma unroll
    for (int j0 = 0; j0 < 9; ++j0) {
      const int off = (j0 * 256 + tid) * 8;
      const int t16 = off >> 10;            // rs*2 + pl
      const int j = off & 1023;
      const int rs = t16 >> 1, pl = t16 & 1;
      const u16* s = wpk + (long)rs * (ICB * 8192) + (long)icb * 8192
                   + pl * 4096 + ocq * 1024 + j;
      *reinterpret_cast<uint4*>(&smem[t16 * 1024 + j]) =
          *reinterpret_cast<const uint4*>(s);
    }
    // ---- per-lane row base pointers into padded input
    const u16* rb[4];
    #pragma unroll
    for (int jr = 0; jr < 4; ++jr)
      rb[jr] = in + ((((long)b * H2 + hw0 + jr) * ICB + icb) * W2 + (w0 + pxw + lm)) * 32
             + lq * 8;
    __syncthreads();

    #pragma unroll
    for (int r = 0; r < 3; ++r)
      #pragma unroll
      for (int s = 0; s < 3; ++s) {
        const int rs = r * 3 + s;
        f16x8 bb[2][2];
        #pragma unroll
        for (int jj = 0; jj < 2; ++jj)
          #pragma unroll
          for (int f = 0; f < 2; ++f)
            bb[jj][f] = *reinterpret_cast<const f16x8*>(rb[jj + r] + (f * 16 + s) * 32);
        const int tb = rs * 2048;
        const f16x8 a0h = *reinterpret_cast<const f16x8*>(&smem[tb + aswz0]);
        const f16x8 a0l = *reinterpret_cast<const f16x8*>(&smem[tb + 1024 + aswz0]);
        const f16x8 a1h = *reinterpret_cast<const f16x8*>(&smem[tb + aswz1]);
        const f16x8 a1l = *reinterpret_cast<const f16x8*>(&smem[tb + 1024 + aswz1]);
        #pragma unroll
        for (int jj = 0; jj < 2; ++jj)
          #pragma unroll
          for (int f = 0; f < 2; ++f) {
            acc[0][jj][f] = MFMA16F(a0h, bb[jj][f], acc[0][jj][f]);
            acc[0][jj][f] = MFMA16F(a0l, bb[jj][f], acc[0][jj][f]);
            acc[1][jj][f] = MFMA16F(a1h, bb[jj][f], acc[1][jj][f]);
            acc[1][jj][f] = MFMA16F(a1l, bb[jj][f], acc[1][jj][f]);
          }
      }
  }

  // ---- epilogue: bias (+relu), swizzled LDS staging, coalesced write
  __syncthreads();
  if (OF16) {
    u16* st = smem;   // [RPB][PXS][32] u16 (16 KB)
    #pragma unroll
    for (int mf = 0; mf < 2; ++mf)
      #pragma unroll
      for (int jj = 0; jj < 2; ++jj)
        #pragma unroll
        for (int f = 0; f < 2; ++f)
          #pragma unroll
          for (int reg = 0; reg < 4; ++reg) {
            const int ocl = mf * 16 + lq * 4 + reg;
            const int px = pxw + f * 16 + lm;
            const int row = rp * 2 + jj;
            float v = fmaxf(acc[mf][jj][f][reg] + bias[ocq * 32 + ocl], 0.f);
            st[(row * PXS + px) * 32 + (ocl ^ ((px & 3) << 3))] =
                __builtin_bit_cast(u16, (_Float16)v);
          }
    __syncthreads();
    u16* og = (u16*)outp;
    const int tot = RPB * PXS * 4;   // us8 chunks
    for (int i = tid; i < tot; i += 256) {
      const int o8 = i & 3, pxr = i >> 2;
      const int px = pxr % PXS, row = pxr / PXS;
      us8 val = *reinterpret_cast<const us8*>(
          &st[(row * PXS + px) * 32 + ((o8 * 8) ^ ((px & 3) << 3))]);
      u16* dst = og + ((((long)b * H2 + hb + row + 1) * 4 + ocq) * W2 + (w0 + px + 1)) * 32
               + o8 * 8;
      *reinterpret_cast<us8*>(dst) = val;
    }
  } else {
    float* stf = reinterpret_cast<float*>(smem);   // [RPB][PXS][32] f32 (32 KB)
    #pragma unroll
    for (int mf = 0; mf < 2; ++mf)
      #pragma unroll
      for (int jj = 0; jj < 2; ++jj)
        #pragma unroll
        for (int f = 0; f < 2; ++f)
          #pragma unroll
          for (int reg = 0; reg < 4; ++reg) {
            const int ocl = mf * 16 + lq * 4 + reg;
            const int px = pxw + f * 16 + lm;
            const int row = rp * 2 + jj;
            stf[(row * PXS + px) * 32 + (ocl ^ ((px & 3) << 3))] =
                acc[mf][jj][f][reg] + bias[ocq * 32 + ocl];
          }
    __syncthreads();
    float* og = (float*)outp;
    const int tot = RPB * PXS * 8;   // float4 chunks
    for (int i = tid; i < tot; i += 256) {
      const int o4 = i & 7, pxr = i >> 3;
      const int px = pxr % PXS, row = pxr / PXS;
      float4 val = *reinterpret_cast<const float4*>(
          &stf[(row * PXS + px) * 32 + ((o4 * 4) ^ ((px & 3) << 3))]);
      *reinterpret_cast<float4*>(
          &og[(((long)b * IH + hb + row) * IW + w0 + px) * 128 + ocq * 32 + o4 * 4]) = val;
    }
  }
}

// ---- attention: one block per (b, n). 128 threads.
__global__ __launch_bounds__(128) void attn_k(
    const float* __restrict__ q_cl, const float* __restrict__ k_cl,
    const float* __restrict__ zcl, const int* __restrict__ u,
    float* __restrict__ out)
{
  constexpr float SCALE = 0.08838834764831845f;  // 128^-0.5
  const int n = blockIdx.x, b = blockIdx.y;
  const int t = threadIdx.x;

  __shared__ float qs[128];
  __shared__ float logit[32];
  __shared__ float el[32];

  int widx = u[b * 4096 + n];
  widx = widx < 0 ? 0 : (widx > 511 ? 511 : widx);

  qs[t] = q_cl[((long)b * 4096 + n) * 128 + t];
  __syncthreads();

  const int h = t >> 2, quad = t & 3;
  const float* kcol = k_cl + (((long)b * 32 + h) * 512 + widx) * 128 + quad * 32;
  float p = 0.f;
  #pragma unroll
  for (int j = 0; j < 32; j += 4) {
    const float4 kv = *reinterpret_cast<const float4*>(kcol + j);
    p = fmaf(qs[quad * 32 + j + 0], kv.x, p);
    p = fmaf(qs[quad * 32 + j + 1], kv.y, p);
    p = fmaf(qs[quad * 32 + j + 2], kv.z, p);
    p = fmaf(qs[quad * 32 + j + 3], kv.w, p);
  }
  p += __shfl_xor(p, 1);
  p += __shfl_xor(p, 2);
  if (quad == 0) logit[h] = p * SCALE;
  __syncthreads();

  float m = -3.4e38f;
  #pragma unroll
  for (int h2 = 0; h2 < 32; ++h2) m = fmaxf(m, logit[h2]);
  if (t < 32) el[t] = __expf(logit[t] - m);
  __syncthreads();
  float den = 0.f;
  #pragma unroll
  for (int h2 = 0; h2 < 32; ++h2) den += el[h2];

  const float* zcol = zcl + ((long)b * 32 * 512 + widx) * 128 + t;
  float o0 = 0.f, o1 = 0.f, o2 = 0.f, o3 = 0.f;
  #pragma unroll
  for (int h2 = 0; h2 < 32; h2 += 4) {
    o0 = fmaf(el[h2 + 0], zcol[(long)(h2 + 0) * 512 * 128], o0);
    o1 = fmaf(el[h2 + 1], zcol[(long)(h2 + 1) * 512 * 128], o1);
    o2 = fmaf(el[h2 + 2], zcol[(long)(h2 + 2) * 512 * 128], o2);
    o3 = fmaf(el[h2 + 3], zcol[(long)(h2 + 3) * 512 * 128], o3);
  }
  out[((long)b * 4096 + n) * 128 + t] = ((o0 + o1) + (o2 + o3)) / den;
}

extern "C" void kernel_launch(void* const* d_in, const int* in_sizes, int n_in,
                              void* d_out, int out_size, void* d_ws, size_t ws_size,
                              hipStream_t stream) {
  const float* x   = (const float*)d_in[0];
  const float* y   = (const float*)d_in[1];
  const float* z   = (const float*)d_in[2];
  const int*   u   = (const int*)  d_in[3];
  const float* wq1 = (const float*)d_in[4];
  const float* bq1 = (const float*)d_in[5];
  const float* wq2 = (const float*)d_in[6];
  const float* bq2 = (const float*)d_in[7];
  const float* wk1 = (const float*)d_in[8];
  const float* bk1 = (const float*)d_in[9];
  const float* wk2 = (const float*)d_in[10];
  const float* bk2 = (const float*)d_in[11];
  float* out = (float*)d_out;
  u16* wsu = (u16*)d_ws;

  // ---- arena (u16 offsets); total 74.8 MB
  u16*   ypad = wsu + 0;           //  8,947,712  [2][34][8][514][32] f16
  u16*   xpad = wsu + 8947712;     //  2,230,272  [2][66][8][66][32]  f16
  u16*   t2k  = wsu + 11177984;    //  4,473,856  [2][34][4][514][32] f16
  u16*   t1q  = wsu + 15651840;    //  1,115,136  [2][66][4][66][32]  f16
  float* zcl  = (float*)(wsu + 16766976);  // 4,194,304 f32 [2][32][512][128]
  float* k_cl = (float*)(wsu + 25155584);  // 4,194,304 f32 [2][32][512][128]
  float* q_cl = (float*)(wsu + 33544192);  // 1,048,576 f32 [2,4096,128]
  u16* wpk_q1 = wsu + 35641344;    //    589,824 (hi+lo, pre-swizzled)
  u16* wpk_q2 = wsu + 36231168;    //    294,912
  u16* wpk_k1 = wsu + 36526080;    //    589,824
  u16* wpk_k2 = wsu + 37115904;    //    294,912  -> end 37,410,816 u16

  pack_zero_k<<<dim3(511), 256, 0, stream>>>(wq1, wq2, wk1, wk2,
                                             wpk_q1, wpk_q2, wpk_k1, wpk_k2,
                                             ypad, xpad, t2k, t1q);
  cvt_all_k<<<dim3(14336), dim3(32, 8), 0, stream>>>(x, y, z, xpad, ypad, zcl);
  conv_k<8, 1><<<dim3(640), 256, 0, stream>>>(
      ypad, wpk_k1, bk1, (void*)t2k, xpad, wpk_q1, bq1, (void*)t1q);
  conv_k<4, 0><<<dim3(640), 256, 0, stream>>>(
      t2k, wpk_k2, bk2, (void*)k_cl, t1q, wpk_q2, bq2, (void*)q_cl);
  attn_k<<<dim3(4096, 2), 128, 0, stream>>>(q_cl, k_cl, zcl, u, out);
}